// Round 3
// baseline (214.355 us; speedup 1.0000x reference)
//
#include <hip/hip_runtime.h>

typedef __attribute__((ext_vector_type(8))) short bf16x8;
typedef __attribute__((ext_vector_type(4))) short bf16x4;
typedef __attribute__((ext_vector_type(4))) float f32x4;
typedef __attribute__((ext_vector_type(16))) float f32x16;

#define MFMA16(a,b,c) __builtin_amdgcn_mfma_f32_16x16x32_bf16((a),(b),(c),0,0,0)
#define MFMA32(a,b,c) __builtin_amdgcn_mfma_f32_32x32x16_bf16((a),(b),(c),0,0,0)

__device__ __forceinline__ short f2bf(float f) {
  union { float f; unsigned u; } v; v.f = f;
  unsigned r = v.u + 0x7FFFu + ((v.u >> 16) & 1u);   // RNE
  return (short)(r >> 16);
}
__device__ __forceinline__ float bf2f(short s) {
  union { unsigned u; float f; } v; v.u = ((unsigned)(unsigned short)s) << 16;
  return v.f;
}
__device__ __forceinline__ unsigned cvtpk(float lo, float hi) {
  unsigned d;
  asm("v_cvt_pk_bf16_f32 %0, %1, %2" : "=v"(d) : "v"(lo), "v"(hi));
  return d;
}
__device__ __forceinline__ void async16(const void* g, void* l) {
  __builtin_amdgcn_global_load_lds(
      (const __attribute__((address_space(1))) unsigned*)g,
      (__attribute__((address_space(3))) unsigned*)l, 16, 0, 0);
}

// ------------- convert Wq/Wk/Wv fp32 -> bf16 [3][256][256] -------------
__global__ void cvt_w_kernel(const float* __restrict__ Wq, const float* __restrict__ Wk,
                             const float* __restrict__ Wv, short* __restrict__ Wb) {
  int v = blockIdx.x * 256 + threadIdx.x;        // 24576 units of 8 elems
  int z = v >> 13, r = v & 8191;
  const float* src = ((z == 0) ? Wq : (z == 1) ? Wk : Wv) + r * 8;
  float4 a = *(const float4*)src;
  float4 b = *(const float4*)(src + 4);
  bf16x8 h;
  h[0]=f2bf(a.x); h[1]=f2bf(a.y); h[2]=f2bf(a.z); h[3]=f2bf(a.w);
  h[4]=f2bf(b.x); h[5]=f2bf(b.y); h[6]=f2bf(b.z); h[7]=f2bf(b.w);
  *(bf16x8*)(Wb + z * 65536 + r * 8) = h;
}

// ------------- proj: BM=128, x staged once, z-outer; W loaded once/block -------------
__global__ __launch_bounds__(256, 2) void proj_kernel(
    const float* __restrict__ x, const short* __restrict__ Wb,
    const float* __restrict__ bq, const float* __restrict__ bk, const float* __restrict__ bv,
    short* __restrict__ Qb, short* __restrict__ Kb, short* __restrict__ VTb)
{
  __shared__ __attribute__((aligned(16))) char xs[65536]; // x tile [128][256] bf16, swizzled
  const int tid = threadIdx.x;
  const int lane = tid & 63;
  const int w = tid >> 6;
  const int l15 = lane & 15, lg = lane >> 4;
  const int m0 = blockIdx.x * 128;
  const int batch = m0 >> 12;
  const int s0 = m0 & 4095;

  #pragma unroll
  for (int c = 0; c < 16; ++c) {
    int v = c * 256 + tid;          // 4096 16B-units
    int row = v >> 5, u = v & 31;
    const float* g = x + (size_t)(m0 + row) * 256 + u * 8;
    float4 a = *(const float4*)g;
    float4 b = *(const float4*)(g + 4);
    bf16x8 h;
    h[0]=f2bf(a.x); h[1]=f2bf(a.y); h[2]=f2bf(a.z); h[3]=f2bf(a.w);
    h[4]=f2bf(b.x); h[5]=f2bf(b.y); h[6]=f2bf(b.z); h[7]=f2bf(b.w);
    *(bf16x8*)(xs + row * 512 + ((u ^ (row & 7)) * 16)) = h;
  }
  __syncthreads();

  for (int z = 0; z < 3; ++z) {
    const short* Wz = Wb + z * 65536;
    bf16x8 wf[4][8];
    #pragma unroll
    for (int fc = 0; fc < 4; ++fc)
      #pragma unroll
      for (int ks = 0; ks < 8; ++ks)
        wf[fc][ks] = *(const bf16x8*)(Wz + (size_t)(w*64 + fc*16 + l15) * 256 + ks*32 + lg*8);

    if (z < 2) {
      const float* bias = z ? bk : bq;
      short* Ob = z ? Kb : Qb;
      const float scl = z ? 1.0f : 0.0625f;
      float bb[4];
      #pragma unroll
      for (int fc = 0; fc < 4; ++fc) bb[fc] = bias[w*64 + fc*16 + l15];
      #pragma unroll
      for (int ms = 0; ms < 8; ++ms) {
        bf16x8 xa[8];
        #pragma unroll
        for (int ks = 0; ks < 8; ++ks) {
          int row = ms * 16 + l15;
          xa[ks] = *(const bf16x8*)(xs + row * 512 + (((ks*4 + lg) ^ (row & 7)) * 16));
        }
        f32x4 acc[4];
        #pragma unroll
        for (int fc = 0; fc < 4; ++fc) acc[fc] = (f32x4){0.f,0.f,0.f,0.f};
        #pragma unroll
        for (int ks = 0; ks < 8; ++ks)
          #pragma unroll
          for (int fc = 0; fc < 4; ++fc)
            acc[fc] = MFMA16(xa[ks], wf[fc][ks], acc[fc]);
        #pragma unroll
        for (int fc = 0; fc < 4; ++fc)
          #pragma unroll
          for (int r = 0; r < 4; ++r)
            Ob[(size_t)(m0 + ms*16 + lg*4 + r) * 256 + w*64 + fc*16 + l15] =
                f2bf((acc[fc][r] + bb[fc]) * scl);
      }
    } else {
      float bvr[4][4];
      #pragma unroll
      for (int fr = 0; fr < 4; ++fr)
        #pragma unroll
        for (int r = 0; r < 4; ++r) bvr[fr][r] = bv[w*64 + fr*16 + lg*4 + r];
      #pragma unroll
      for (int ms = 0; ms < 8; ++ms) {
        bf16x8 xa[8];
        #pragma unroll
        for (int ks = 0; ks < 8; ++ks) {
          int row = ms * 16 + l15;
          xa[ks] = *(const bf16x8*)(xs + row * 512 + (((ks*4 + lg) ^ (row & 7)) * 16));
        }
        f32x4 acc[4];
        #pragma unroll
        for (int fr = 0; fr < 4; ++fr) acc[fr] = (f32x4){0.f,0.f,0.f,0.f};
        #pragma unroll
        for (int ks = 0; ks < 8; ++ks)
          #pragma unroll
          for (int fr = 0; fr < 4; ++fr)
            acc[fr] = MFMA16(wf[fr][ks], xa[ks], acc[fr]);
        #pragma unroll
        for (int fr = 0; fr < 4; ++fr)
          #pragma unroll
          for (int r = 0; r < 4; ++r) {
            int e = w*64 + fr*16 + lg*4 + r;
            VTb[(size_t)(batch*256 + e) * 4096 + s0 + ms*16 + l15] = f2bf(acc[fr][r] + bvr[fr][r]);
          }
      }
    }
  }
}

// ------------- flash attention: 8 independent waves (qs 0..3 x kh 0..1), register-P,
// ------------- full-D O^T partial per wave, ONE barrier/tile. kh merged in-block.
__global__ __launch_bounds__(512, 2) void attn_kernel(
    const short* __restrict__ Qb, const short* __restrict__ Kb,
    const short* __restrict__ VTb, short* __restrict__ Op, float* __restrict__ mlg)
{
  // [K0 32K][K1 32K][VT0 32K][VT1 32K]; epilogue reuses [0..2K ml][4K.. 68K xt]
  __shared__ __attribute__((aligned(16))) char smem[131072];
  const int tid = threadIdx.x;
  const int lane = tid & 63;
  const int w = tid >> 6;
  const int l31 = lane & 31, hi = lane >> 5;
  const int qs = w & 3, kh = w >> 2;

  const int b = blockIdx.x;
  const int xcd = b & 7;
  const int batch = xcd >> 1, ns = xcd & 1;
  const int qt = b >> 3;
  const int q0 = qt * 128;
  const int kvbase = ns * 2048;

  const char* Kg = (const char*)(Kb  + (size_t)batch * 4096 * 256);
  const char* Vg = (const char*)(VTb + (size_t)batch * 256 * 4096);

  bf16x8 qf[16];
  {
    const short* qrow = Qb + (size_t)(batch*4096 + q0 + qs*32 + l31) * 256;
    #pragma unroll
    for (int ks = 0; ks < 16; ++ks) qf[ks] = *(const bf16x8*)(qrow + ks*16 + hi*8);
  }

  f32x16 o[8];
  #pragma unroll
  for (int i = 0; i < 8; ++i)
    #pragma unroll
    for (int r = 0; r < 16; ++r) o[i][r] = 0.f;
  float m_run = -1e30f, l_run = 0.f;

  auto stage = [&](int buf, int kv0) {
    char* kl = smem + buf * 32768;
    #pragma unroll
    for (int c = 0; c < 4; ++c) {
      int v = c * 512 + tid;
      int row = v >> 5, s = v & 31;
      async16(Kg + (size_t)(kv0 + row) * 512 + ((s ^ (row & 7)) * 16),
              kl + (c * 512 + w * 64) * 16);
    }
    char* vl = smem + 65536 + buf * 32768;
    #pragma unroll
    for (int c = 0; c < 4; ++c) {
      int v = c * 512 + tid;
      int row = v >> 3, s = v & 7;
      async16(Vg + (size_t)row * 8192 + (size_t)kv0 * 2 + ((s ^ (row & 7)) * 16),
              vl + (c * 512 + w * 64) * 16);
    }
  };

  stage(0, kvbase);
  __syncthreads();

  for (int t = 0; t < 32; ++t) {
    const int cur = t & 1;
    if (t < 31) stage(cur ^ 1, kvbase + (t + 1) * 64);

    const char* kl = smem + cur * 32768;
    const char* vl = smem + 65536 + cur * 32768;

    // QK^T swapped: st = S^T[kv = kh*32 + (r&3)+8*(r>>2)+4*hi][q = l31]
    f32x16 st;
    #pragma unroll
    for (int r = 0; r < 16; ++r) st[r] = 0.f;
    __builtin_amdgcn_s_setprio(1);
    #pragma unroll
    for (int ks = 0; ks < 16; ++ks) {
      int row = kh * 32 + l31;
      bf16x8 kf = *(const bf16x8*)(kl + row * 512 + (((ks*2 + hi) ^ (row & 7)) * 16));
      st = MFMA32(kf, qf[ks], st);
    }
    __builtin_amdgcn_s_setprio(0);

    // independent online softmax (per q = l31, over this wave's kv-half subset)
    float mx = st[0];
    #pragma unroll
    for (int r = 1; r < 16; ++r) mx = fmaxf(mx, st[r]);
    mx = fmaxf(mx, __shfl_xor(mx, 32));
    float m_new = fmaxf(m_run, mx);
    if (m_new > m_run) {
      float alpha = __expf(m_run - m_new);
      l_run *= alpha;
      #pragma unroll
      for (int df = 0; df < 8; ++df) o[df] = o[df] * alpha;
      m_run = m_new;
    }
    float lsum = 0.f;
    #pragma unroll
    for (int r = 0; r < 16; ++r) { st[r] = __expf(st[r] - m_run); lsum += st[r]; }
    l_run += lsum;

    // pack P to B-frags in-register (cvt_pk + shfl_xor32 + select)
    bf16x8 pa[2];
    #pragma unroll
    for (int kvf = 0; kvf < 2; ++kvf) {
      float s0_ = st[8*kvf+0], s1_ = st[8*kvf+1], s2_ = st[8*kvf+2], s3_ = st[8*kvf+3];
      float s4_ = st[8*kvf+4], s5_ = st[8*kvf+5], s6_ = st[8*kvf+6], s7_ = st[8*kvf+7];
      unsigned X  = cvtpk(s0_, s1_);
      unsigned X2 = cvtpk(s2_, s3_);
      unsigned Y  = cvtpk(s4_, s5_);
      unsigned Y2 = cvtpk(s6_, s7_);
      unsigned Xs  = __shfl_xor((int)X, 32);
      unsigned X2s = __shfl_xor((int)X2, 32);
      unsigned Ys  = __shfl_xor((int)Y, 32);
      unsigned Y2s = __shfl_xor((int)Y2, 32);
      union { unsigned u[4]; bf16x8 v; } fr;
      fr.u[0] = hi ? Ys  : X;
      fr.u[1] = hi ? Y2s : X2;
      fr.u[2] = hi ? Y   : Xs;
      fr.u[3] = hi ? Y2  : X2s;
      pa[kvf] = fr.v;
    }

    // PV: O^T[d][q] += VT-frag(A,m=d) x P-frag(B,n=q), full d=256, own kv-half
    __builtin_amdgcn_s_setprio(1);
    #pragma unroll
    for (int kvf = 0; kvf < 2; ++kvf) {
      #pragma unroll
      for (int df = 0; df < 8; ++df) {
        int row = df * 32 + l31;
        int u = (kh*2 + kvf) * 2 + hi;
        bf16x8 vb = *(const bf16x8*)(vl + row * 128 + ((u ^ (row & 7)) * 16));
        o[df] = MFMA32(vb, pa[kvf], o[df]);
      }
    }
    __builtin_amdgcn_s_setprio(0);

    __syncthreads();   // buffer swap + drains prefetch
  }

  // ---- epilogue: merge kh pair in-block, store bf16 partial + (m,l) per ns ----
  float lt = l_run + __shfl_xor(l_run, 32);
  float* ml = (float*)smem;                      // [2][4][32][2]
  if (!hi) {
    float2 v = {m_run, lt};
    *(float2*)(ml + ((kh*4 + qs)*32 + l31)*2) = v;
  }
  __syncthreads();
  float2 other = *(const float2*)(ml + (((kh^1)*4 + qs)*32 + l31)*2);
  float m_star = fmaxf(m_run, other.x);
  float a_own = __expf(m_run - m_star);
  float l_star = a_own * lt + __expf(other.x - m_star) * other.y;
  char* xt = smem + 4096 + qs * 16384;           // [32 q][512B] bf16 exchange, swizzled 8B units

  if (kh == 1) {
    #pragma unroll
    for (int df = 0; df < 8; ++df)
      #pragma unroll
      for (int g = 0; g < 4; ++g) {
        bf16x4 pv;
        #pragma unroll
        for (int c = 0; c < 4; ++c) pv[c] = f2bf(o[df][4*g + c] * a_own);
        int u = (df*32 + 8*g + 4*hi) >> 2;
        *(bf16x4*)(xt + l31*512 + ((u ^ (l31 & 7)) * 8)) = pv;
      }
  }
  __syncthreads();
  if (kh == 0) {
    const int qglob = batch*4096 + q0 + qs*32 + l31;
    short* op = Op + ((size_t)ns * 16384 + qglob) * 256;
    #pragma unroll
    for (int df = 0; df < 8; ++df)
      #pragma unroll
      for (int g = 0; g < 4; ++g) {
        int u = (df*32 + 8*g + 4*hi) >> 2;
        bf16x4 p1 = *(const bf16x4*)(xt + l31*512 + ((u ^ (l31 & 7)) * 8));
        bf16x4 pv;
        #pragma unroll
        for (int c = 0; c < 4; ++c)
          pv[c] = f2bf(o[df][4*g + c] * a_own + bf2f(p1[c]));
        *(bf16x4*)(op + df*32 + 8*g + 4*hi) = pv;
      }
    if (!hi) {
      mlg[((size_t)ns*16384 + qglob)*2]     = m_star;
      mlg[((size_t)ns*16384 + qglob)*2 + 1] = l_star;
    }
  }
}

// ------------- combine the two kv-split partials (bf16 in, fp32 out) -------------
__global__ void combine_kernel(const short* __restrict__ Op, const float* __restrict__ mlg,
                               float* __restrict__ out) {
  int idx = blockIdx.x * 256 + threadIdx.x;     // 524288 = 16384 rows x 32 chunks
  int row = idx >> 5, c = idx & 31;
  float m0 = mlg[row * 2],           l0 = mlg[row * 2 + 1];
  float m1 = mlg[(16384 + row) * 2], l1 = mlg[(16384 + row) * 2 + 1];
  float ms = fmaxf(m0, m1);
  float a0 = __expf(m0 - ms), a1 = __expf(m1 - ms);
  float inv = 1.0f / (l0 * a0 + l1 * a1);
  a0 *= inv; a1 *= inv;
  bf16x8 v0 = *(const bf16x8*)(Op + (size_t)row * 256 + c * 8);
  bf16x8 v1 = *(const bf16x8*)(Op + (size_t)(16384 + row) * 256 + c * 8);
  float4 r0, r1;
  r0.x = a0*bf2f(v0[0]) + a1*bf2f(v1[0]);
  r0.y = a0*bf2f(v0[1]) + a1*bf2f(v1[1]);
  r0.z = a0*bf2f(v0[2]) + a1*bf2f(v1[2]);
  r0.w = a0*bf2f(v0[3]) + a1*bf2f(v1[3]);
  r1.x = a0*bf2f(v0[4]) + a1*bf2f(v1[4]);
  r1.y = a0*bf2f(v0[5]) + a1*bf2f(v1[5]);
  r1.z = a0*bf2f(v0[6]) + a1*bf2f(v1[6]);
  r1.w = a0*bf2f(v0[7]) + a1*bf2f(v1[7]);
  float* po = out + (size_t)row * 256 + c * 8;
  *(float4*)po = r0;
  *(float4*)(po + 4) = r1;
}

extern "C" void kernel_launch(void* const* d_in, const int* in_sizes, int n_in,
                              void* d_out, int out_size, void* d_ws, size_t ws_size,
                              hipStream_t stream) {
  const float* x  = (const float*)d_in[0];
  const float* Wq = (const float*)d_in[1];
  const float* bq = (const float*)d_in[2];
  const float* Wk = (const float*)d_in[3];
  const float* bk = (const float*)d_in[4];
  const float* Wv = (const float*)d_in[5];
  const float* bv = (const float*)d_in[6];
  float* out = (float*)d_out;

  char* ws = (char*)d_ws;
  short* Qb  = (short*)(ws);                         // 8 MiB  [16384][256] bf16 (1/16 folded)
  short* Kb  = (short*)(ws + 8388608);               // 8 MiB  [16384][256] bf16
  short* VTb = (short*)(ws + 16777216);              // 8 MiB  [4][256][4096] bf16
  short* Wb  = (short*)(ws + 25165824);              // 384 KiB [3][256][256] bf16
  float* mlg = (float*)(ws + 25559040);              // 256 KiB [2][16384][2] f32
  short* Op  = (short*)(ws + 25821184);              // 16 MiB [2][16384][256] bf16

  cvt_w_kernel<<<dim3(96), dim3(256), 0, stream>>>(Wq, Wk, Wv, Wb);
  proj_kernel<<<dim3(128), dim3(256), 0, stream>>>(x, Wb, bq, bk, bv, Qb, Kb, VTb);
  attn_kernel<<<dim3(256), dim3(512), 0, stream>>>(Qb, Kb, VTb, Op, mlg);
  combine_kernel<<<dim3(2048), dim3(256), 0, stream>>>(Op, mlg, out);
}